// Round 1
// baseline (184.637 us; speedup 1.0000x reference)
//
#include <hip/hip_runtime.h>
#include <stdint.h>

#define N2 2048
#define NN (2048UL * 2048UL)
#define BM 128
#define BN 128
#define BK 32

typedef __attribute__((ext_vector_type(8))) short short8;
typedef __attribute__((ext_vector_type(4))) float f32x4;

__device__ __forceinline__ unsigned short f2bf(float f) {
    unsigned int u = __float_as_uint(f);
    u += 0x7FFFu + ((u >> 16) & 1u);   // round-to-nearest-even
    return (unsigned short)(u >> 16);
}

__device__ __forceinline__ void gload16(const void* g, void* l) {
    __builtin_amdgcn_global_load_lds(
        (const __attribute__((address_space(1))) unsigned int*)g,
        (__attribute__((address_space(3))) unsigned int*)l, 16, 0, 0);
}

// ---------------------------------------------------------------------------
// combine: HA[c][n][m] = sum_e s1[c][e] A[e][n][m]   (bf16, row-major)
//          HBt[c][m][n] = sum_e s2[c][e] A[e][n][m]  (bf16, transposed)
//          HB2t[c][m][n] = sum_e s3[c][e] A[e][n][m] (bf16, transposed)
// ---------------------------------------------------------------------------
__global__ __launch_bounds__(256) void combine_kernel(
    const float* __restrict__ A, const float* __restrict__ w01,
    const float* __restrict__ w02, const float* __restrict__ w11,
    unsigned short* __restrict__ HA, unsigned short* __restrict__ HBt,
    unsigned short* __restrict__ HB2t) {
    __shared__ float s[3][2][5];
    __shared__ float tile[32][33];
    const int tid = threadIdx.x;
    if (tid < 6) {
        const int wi = tid >> 1, c = tid & 1;
        const float* w = (wi == 0 ? w01 : (wi == 1 ? w02 : w11)) + c * 5;
        float mx = w[0];
        for (int e = 1; e < 5; e++) mx = fmaxf(mx, w[e]);
        float ex[5], sum = 0.f;
        for (int e = 0; e < 5; e++) { ex[e] = expf(w[e] - mx); sum += ex[e]; }
        for (int e = 0; e < 5; e++) s[wi][c][e] = ex[e] / sum;
    }
    __syncthreads();

    const int row = tid >> 3;          // 0..31
    const int c4  = (tid & 7) << 2;    // 0,4,...,28
    const size_t n = (size_t)blockIdx.y * 32 + row;
    const size_t m = (size_t)blockIdx.x * 32 + c4;

    float acc[6][4] = {};
    #pragma unroll
    for (int e = 0; e < 5; e++) {
        const float4 a = *(const float4*)&A[(size_t)e * NN + n * N2 + m];
        const float av[4] = {a.x, a.y, a.z, a.w};
        #pragma unroll
        for (int c = 0; c < 2; c++) {
            const float s0 = s[0][c][e], s1 = s[1][c][e], s2 = s[2][c][e];
            #pragma unroll
            for (int i = 0; i < 4; i++) {
                acc[c][i]     += s0 * av[i];
                acc[2 + c][i] += s1 * av[i];
                acc[4 + c][i] += s2 * av[i];
            }
        }
    }
    // HA row-major (bf16)
    #pragma unroll
    for (int c = 0; c < 2; c++) {
        ushort4 v;
        v.x = f2bf(acc[c][0]); v.y = f2bf(acc[c][1]);
        v.z = f2bf(acc[c][2]); v.w = f2bf(acc[c][3]);
        *(ushort4*)&HA[(size_t)c * NN + n * N2 + m] = v;
    }
    // transposed outputs through LDS
    for (int r = 0; r < 4; r++) {   // r: 0=HB c0, 1=HB c1, 2=HB2 c0, 3=HB2 c1
        __syncthreads();
        #pragma unroll
        for (int i = 0; i < 4; i++) tile[row][c4 + i] = acc[2 + r][i];
        __syncthreads();
        unsigned short* dst = (r < 2 ? HBt : HB2t) + (size_t)(r & 1) * NN
                            + ((size_t)blockIdx.x * 32 + row) * N2
                            + (size_t)blockIdx.y * 32 + c4;
        ushort4 v;
        v.x = f2bf(tile[c4 + 0][row]); v.y = f2bf(tile[c4 + 1][row]);
        v.z = f2bf(tile[c4 + 2][row]); v.w = f2bf(tile[c4 + 3][row]);
        *(ushort4*)dst = v;
    }
}

// ---------------------------------------------------------------------------
// bf16 GEMM, B^T input: C[c] = A[c] @ B[c],  Bt rows are B columns.
// 128x128 tile, BK=32, 4 waves (2x2), each wave 64x64 = 4x4 frags 16x16x32.
// ---------------------------------------------------------------------------
__global__ __launch_bounds__(256) void gemm_bt(
    const unsigned short* __restrict__ A, const unsigned short* __restrict__ Bt,
    float* __restrict__ C) {
    __shared__ unsigned short As[BM * BK];   // 8 KB
    __shared__ unsigned short Bs[BN * BK];   // 8 KB

    const int tid  = threadIdx.x;
    const int wave = tid >> 6, lane = tid & 63;
    const int wrow = (wave >> 1) * 64, wcol = (wave & 1) * 64;
    const int l16 = lane & 15, lhi = lane >> 4;

    const int brow = blockIdx.y * BM;
    const int bcol = blockIdx.x * BN;
    const size_t cz = (size_t)blockIdx.z * NN;
    const unsigned short* Ab  = A  + cz + (size_t)brow * N2;
    const unsigned short* Btb = Bt + cz + (size_t)bcol * N2;
    float* Cb = C + cz + (size_t)brow * N2 + bcol;

    f32x4 acc[4][4] = {};

    const int sr = tid >> 2;          // 0..63 (row within 64-row chunk)
    const int sc = (tid & 3) * 8;     // bf16 col offset

    for (int k0 = 0; k0 < N2; k0 += BK) {
        gload16(Ab  + (size_t)sr * N2 + k0 + sc,        As + tid * 8);
        gload16(Ab  + (size_t)(sr + 64) * N2 + k0 + sc, As + 2048 + tid * 8);
        gload16(Btb + (size_t)sr * N2 + k0 + sc,        Bs + tid * 8);
        gload16(Btb + (size_t)(sr + 64) * N2 + k0 + sc, Bs + 2048 + tid * 8);
        __syncthreads();

        short8 af[4], bf[4];
        #pragma unroll
        for (int m = 0; m < 4; m++)
            af[m] = *(const short8*)&As[(wrow + m * 16 + l16) * BK + lhi * 8];
        #pragma unroll
        for (int nn = 0; nn < 4; nn++)
            bf[nn] = *(const short8*)&Bs[(wcol + nn * 16 + l16) * BK + lhi * 8];
        #pragma unroll
        for (int m = 0; m < 4; m++)
            #pragma unroll
            for (int nn = 0; nn < 4; nn++)
                acc[m][nn] = __builtin_amdgcn_mfma_f32_16x16x32_bf16(
                    af[m], bf[nn], acc[m][nn], 0, 0, 0);
        __syncthreads();
    }

    #pragma unroll
    for (int m = 0; m < 4; m++) {
        const int r0 = wrow + m * 16 + lhi * 4;
        #pragma unroll
        for (int nn = 0; nn < 4; nn++) {
            const int c0 = wcol + nn * 16 + l16;
            #pragma unroll
            for (int j = 0; j < 4; j++)
                Cb[(size_t)(r0 + j) * N2 + c0] = acc[m][nn][j];
        }
    }
}

// ---------------------------------------------------------------------------
// row normalize: dinv = rsqrt(rowsum) (0 if rowsum<=0)
// ---------------------------------------------------------------------------
__device__ __forceinline__ float block_sum256(float v) {
    #pragma unroll
    for (int off = 32; off; off >>= 1) v += __shfl_xor(v, off, 64);
    __shared__ float wsum[4];
    if ((threadIdx.x & 63) == 0) wsum[threadIdx.x >> 6] = v;
    __syncthreads();
    return wsum[0] + wsum[1] + wsum[2] + wsum[3];
}

__global__ __launch_bounds__(256) void norm0_kernel(
    const float* __restrict__ H, unsigned short* __restrict__ Hn) {
    const size_t r = blockIdx.x;             // 0..4095 (c*2048 + row)
    const float* hr = H + r * N2;
    const int base = threadIdx.x * 8;
    float v[8];
    #pragma unroll
    for (int i = 0; i < 4; i++) {
        const float2 t = *(const float2*)&hr[base + i * 2];
        v[2 * i] = t.x; v[2 * i + 1] = t.y;
    }
    float s = 0.f;
    #pragma unroll
    for (int i = 0; i < 8; i++) s += v[i];
    const float tot = block_sum256(s);
    const float dinv = tot > 0.f ? rsqrtf(tot) : 0.f;
    ushort4 o0, o1;
    o0.x = f2bf(v[0] * dinv); o0.y = f2bf(v[1] * dinv);
    o0.z = f2bf(v[2] * dinv); o0.w = f2bf(v[3] * dinv);
    o1.x = f2bf(v[4] * dinv); o1.y = f2bf(v[5] * dinv);
    o1.z = f2bf(v[6] * dinv); o1.w = f2bf(v[7] * dinv);
    *(ushort4*)&Hn[r * N2 + base]     = o0;
    *(ushort4*)&Hn[r * N2 + base + 4] = o1;
}

__global__ __launch_bounds__(256) void norm1_kernel(float* __restrict__ H) {
    const size_t r = blockIdx.x;
    float* hr = H + r * N2;
    const int base = threadIdx.x * 8;
    float v[8];
    #pragma unroll
    for (int i = 0; i < 4; i++) {
        const float2 t = *(const float2*)&hr[base + i * 2];
        v[2 * i] = t.x; v[2 * i + 1] = t.y;
    }
    float s = 0.f;
    #pragma unroll
    for (int i = 0; i < 8; i++) s += v[i];
    const float tot = block_sum256(s);
    const float dinv = tot > 0.f ? rsqrtf(tot) : 0.f;
    #pragma unroll
    for (int i = 0; i < 4; i++) {
        float2 t;
        t.x = v[2 * i] * dinv; t.y = v[2 * i + 1] * dinv;
        *(float2*)&hr[base + i * 2] = t;
    }
}

// ---------------------------------------------------------------------------
// head: y[t,o] = lin_b[o] + sum_k relu(X[tx[t]]·gcn_w[k] + gcn_b[k]) *
//                           (lin_w[o,k] + lin_w[o,k+128])
// ---------------------------------------------------------------------------
__global__ __launch_bounds__(128) void head_kernel(
    const float* __restrict__ X, const float* __restrict__ gcn_w,
    const float* __restrict__ gcn_b, const float* __restrict__ lin_w,
    const float* __restrict__ lin_b, const int* __restrict__ tx,
    float* __restrict__ y) {
    __shared__ float xr[512];
    __shared__ float xk[128];
    const int t = blockIdx.x, tid = threadIdx.x;
    const int trg = tx[t];
    const float* Xr = X + (size_t)trg * 512;
    *(float4*)&xr[tid * 4] = *(const float4*)&Xr[tid * 4];
    __syncthreads();
    const float* wr = gcn_w + (size_t)tid * 512;
    float d = 0.f;
    for (int i = 0; i < 512; i += 4) {
        const float4 wv = *(const float4*)&wr[i];
        d += xr[i] * wv.x + xr[i + 1] * wv.y + xr[i + 2] * wv.z + xr[i + 3] * wv.w;
    }
    xk[tid] = fmaxf(d + gcn_b[tid], 0.f);
    __syncthreads();
    if (tid < 8) {
        float a = lin_b[tid];
        for (int k = 0; k < 128; k++)
            a += xk[k] * (lin_w[tid * 256 + k] + lin_w[tid * 256 + 128 + k]);
        y[(size_t)t * 8 + tid] = a;
    }
}

__global__ void wsoft_kernel(const float* __restrict__ w01,
                             const float* __restrict__ w02,
                             const float* __restrict__ w11,
                             float* __restrict__ out) {
    const int tid = threadIdx.x;
    if (tid < 6) {
        const int wi = tid >> 1, c = tid & 1;
        const float* w = (wi == 0 ? w01 : (wi == 1 ? w02 : w11)) + c * 5;
        float mx = w[0];
        for (int e = 1; e < 5; e++) mx = fmaxf(mx, w[e]);
        float ex[5], sum = 0.f;
        for (int e = 0; e < 5; e++) { ex[e] = expf(w[e] - mx); sum += ex[e]; }
        for (int e = 0; e < 5; e++) out[tid * 5 + e] = ex[e] / sum;
    }
}

// ---------------------------------------------------------------------------
extern "C" void kernel_launch(void* const* d_in, const int* in_sizes, int n_in,
                              void* d_out, int out_size, void* d_ws, size_t ws_size,
                              hipStream_t stream) {
    const float* A     = (const float*)d_in[0];
    const float* X     = (const float*)d_in[1];
    const float* w01   = (const float*)d_in[2];
    const float* w02   = (const float*)d_in[3];
    const float* w11   = (const float*)d_in[4];
    const float* gcn_w = (const float*)d_in[5];
    const float* gcn_b = (const float*)d_in[6];
    const float* lin_w = (const float*)d_in[7];
    const float* lin_b = (const float*)d_in[8];
    const int*   tx    = (const int*)d_in[9];

    float* out  = (float*)d_out;
    float* y    = out;           // [512, 8]
    float* allw = out + 4096;    // [3, 2, 5]
    float* H    = out + 4126;    // [2, 2048, 2048] fp32 (GEMM target, normalized in place)

    unsigned short* HA   = (unsigned short*)d_ws;  // [2,N,N] bf16; reused for Hn after layer0
    unsigned short* HBt  = HA + 2 * NN;
    unsigned short* HB2t = HBt + 2 * NN;           // total ws use: 50.3 MB

    combine_kernel<<<dim3(64, 64), 256, 0, stream>>>(A, w01, w02, w11, HA, HBt, HB2t);
    gemm_bt<<<dim3(16, 16, 2), 256, 0, stream>>>(HA, HBt, H);       // H = HA @ HB
    norm0_kernel<<<4096, 256, 0, stream>>>(H, HA);                   // HA buf := bf16 D^-1/2 H
    gemm_bt<<<dim3(16, 16, 2), 256, 0, stream>>>(HA, HB2t, H);      // H = Hn @ HB2
    norm1_kernel<<<4096, 256, 0, stream>>>(H);                       // in-place fp32 normalize
    head_kernel<<<512, 128, 0, stream>>>(X, gcn_w, gcn_b, lin_w, lin_b, tx, y);
    wsoft_kernel<<<1, 64, 0, stream>>>(w01, w02, w11, allw);
}

// Round 2
// 155.469 us; speedup vs baseline: 1.1876x; 1.1876x over previous
//
#include <hip/hip_runtime.h>
#include <stdint.h>

#define N2 2048
#define NN (2048UL * 2048UL)

typedef __attribute__((ext_vector_type(8))) short short8;
typedef __attribute__((ext_vector_type(4))) float f32x4;

__device__ __forceinline__ unsigned short f2bf(float f) {
    unsigned int u = __float_as_uint(f);
    u += 0x7FFFu + ((u >> 16) & 1u);   // round-to-nearest-even
    return (unsigned short)(u >> 16);
}

__device__ __forceinline__ void gload16(const void* g, void* l) {
    __builtin_amdgcn_global_load_lds(
        (const __attribute__((address_space(1))) unsigned int*)g,
        (__attribute__((address_space(3))) unsigned int*)l, 16, 0, 0);
}

// ---------------------------------------------------------------------------
// combine: HA[c][n][m] = sum_e s1[c][e] A[e][n][m]   (bf16, row-major)
//          HBt[c][m][n] = sum_e s2[c][e] A[e][n][m]  (bf16, transposed)
//          HB2t[c][m][n] = sum_e s3[c][e] A[e][n][m] (bf16, transposed)
// ---------------------------------------------------------------------------
__global__ __launch_bounds__(256) void combine_kernel(
    const float* __restrict__ A, const float* __restrict__ w01,
    const float* __restrict__ w02, const float* __restrict__ w11,
    unsigned short* __restrict__ HA, unsigned short* __restrict__ HBt,
    unsigned short* __restrict__ HB2t) {
    __shared__ float s[3][2][5];
    __shared__ float tile[32][33];
    const int tid = threadIdx.x;
    if (tid < 6) {
        const int wi = tid >> 1, c = tid & 1;
        const float* w = (wi == 0 ? w01 : (wi == 1 ? w02 : w11)) + c * 5;
        float mx = w[0];
        for (int e = 1; e < 5; e++) mx = fmaxf(mx, w[e]);
        float ex[5], sum = 0.f;
        for (int e = 0; e < 5; e++) { ex[e] = expf(w[e] - mx); sum += ex[e]; }
        for (int e = 0; e < 5; e++) s[wi][c][e] = ex[e] / sum;
    }
    __syncthreads();

    const int row = tid >> 3;          // 0..31
    const int c4  = (tid & 7) << 2;    // 0,4,...,28
    const size_t n = (size_t)blockIdx.y * 32 + row;
    const size_t m = (size_t)blockIdx.x * 32 + c4;

    float acc[6][4] = {};
    #pragma unroll
    for (int e = 0; e < 5; e++) {
        const float4 a = *(const float4*)&A[(size_t)e * NN + n * N2 + m];
        const float av[4] = {a.x, a.y, a.z, a.w};
        #pragma unroll
        for (int c = 0; c < 2; c++) {
            const float s0 = s[0][c][e], s1 = s[1][c][e], s2 = s[2][c][e];
            #pragma unroll
            for (int i = 0; i < 4; i++) {
                acc[c][i]     += s0 * av[i];
                acc[2 + c][i] += s1 * av[i];
                acc[4 + c][i] += s2 * av[i];
            }
        }
    }
    // HA row-major (bf16)
    #pragma unroll
    for (int c = 0; c < 2; c++) {
        ushort4 v;
        v.x = f2bf(acc[c][0]); v.y = f2bf(acc[c][1]);
        v.z = f2bf(acc[c][2]); v.w = f2bf(acc[c][3]);
        *(ushort4*)&HA[(size_t)c * NN + n * N2 + m] = v;
    }
    // transposed outputs through LDS
    for (int r = 0; r < 4; r++) {   // r: 0=HB c0, 1=HB c1, 2=HB2 c0, 3=HB2 c1
        __syncthreads();
        #pragma unroll
        for (int i = 0; i < 4; i++) tile[row][c4 + i] = acc[2 + r][i];
        __syncthreads();
        unsigned short* dst = (r < 2 ? HBt : HB2t) + (size_t)(r & 1) * NN
                            + ((size_t)blockIdx.x * 32 + row) * N2
                            + (size_t)blockIdx.y * 32 + c4;
        ushort4 v;
        v.x = f2bf(tile[c4 + 0][row]); v.y = f2bf(tile[c4 + 1][row]);
        v.z = f2bf(tile[c4 + 2][row]); v.w = f2bf(tile[c4 + 3][row]);
        *(ushort4*)dst = v;
    }
}

// ---------------------------------------------------------------------------
// bf16 GEMM, B^T input: C[c] = A[c] @ B[c].
// 256x128 block tile, BK=64, 8 waves (4Mx2N), per-wave 64x64 (4x4 frags).
// 3-deep LDS pipeline (T3/T4: counted vmcnt, never 0 in steady state),
// XOR-swizzled LDS (T2), setprio around MFMA cluster (T5).
// LDS per K-tile: A 256x64 (32KB) + B 128x64 (16KB) = 48KB; x3 = 144KB.
// ---------------------------------------------------------------------------
#define GBM 256
#define GBN 128
#define GBK 64
#define TILE_SHORTS 24576   // 48KB in shorts
#define A_SHORTS    16384   // A region per buffer

__global__ __launch_bounds__(512, 2) void gemm_bt2(
    const unsigned short* __restrict__ A, const unsigned short* __restrict__ Bt,
    float* __restrict__ C) {
    __shared__ unsigned short lds[3 * TILE_SHORTS];   // 144 KB

    const int tid  = threadIdx.x;
    const int wave = tid >> 6, lane = tid & 63;
    const int wr = (wave >> 1) * 64;    // 0,64,128,192
    const int wc = (wave & 1) * 64;     // 0,64
    const int l16 = lane & 15, lhi = lane >> 4;
    const int lsw = l16 & 7;            // row-dependent swizzle bits on read

    const int brow = blockIdx.y * GBM;
    const int bcol = blockIdx.x * GBN;
    const size_t cz = (size_t)blockIdx.z * NN;
    const unsigned short* Ab  = A  + cz + (size_t)brow * N2;
    const unsigned short* Btb = Bt + cz + (size_t)bcol * N2;
    float* Cb = C + cz + (size_t)brow * N2 + bcol;

    // staging: thread tid handles LDS 16B-slots (i*512+tid).
    // slot -> (row = slot>>3, stored col-slot = slot&7); logical source
    // col-slot = stored ^ (row&7)  (same involution applied on read).
    const unsigned short* a_src[4];
    #pragma unroll
    for (int i = 0; i < 4; i++) {
        const int slot = i * 512 + tid;
        const int r = slot >> 3, s = (slot & 7) ^ (r & 7);
        a_src[i] = Ab + (size_t)r * N2 + s * 8;
    }
    const unsigned short* b_src[2];
    #pragma unroll
    for (int i = 0; i < 2; i++) {
        const int slot = i * 512 + tid;
        const int r = slot >> 3, s = (slot & 7) ^ (r & 7);
        b_src[i] = Btb + (size_t)r * N2 + s * 8;
    }

    #define STAGE(buf, k0)                                                    \
        do {                                                                  \
            unsigned short* dst = lds + (buf) * TILE_SHORTS + tid * 8;        \
            _Pragma("unroll")                                                 \
            for (int i = 0; i < 4; i++)                                       \
                gload16(a_src[i] + (k0), dst + i * 4096);                     \
            _Pragma("unroll")                                                 \
            for (int i = 0; i < 2; i++)                                       \
                gload16(b_src[i] + (k0), dst + A_SHORTS + i * 4096);          \
        } while (0)

    f32x4 acc[4][4] = {};

    STAGE(0, 0);
    STAGE(1, GBK);

    const int nt = N2 / GBK;   // 32
    for (int t = 0; t < nt; ++t) {
        if (t + 2 < nt) STAGE((t + 2) % 3, (t + 2) * GBK);

        if (t < nt - 2)       asm volatile("s_waitcnt vmcnt(12)" ::: "memory");
        else if (t == nt - 2) asm volatile("s_waitcnt vmcnt(6)"  ::: "memory");
        else                  asm volatile("s_waitcnt vmcnt(0)"  ::: "memory");
        __builtin_amdgcn_s_barrier();          // buf[t%3] ready for all waves

        const unsigned short* base = lds + (t % 3) * TILE_SHORTS;
        short8 af[4][2], bf[4][2];
        #pragma unroll
        for (int m = 0; m < 4; m++) {
            const unsigned short* rowp = base + (wr + m * 16 + l16) * 64;
            #pragma unroll
            for (int ks = 0; ks < 2; ks++)
                af[m][ks] = *(const short8*)(rowp + ((ks * 4 + lhi) ^ lsw) * 8);
        }
        #pragma unroll
        for (int n = 0; n < 4; n++) {
            const unsigned short* rowp = base + A_SHORTS + (wc + n * 16 + l16) * 64;
            #pragma unroll
            for (int ks = 0; ks < 2; ks++)
                bf[n][ks] = *(const short8*)(rowp + ((ks * 4 + lhi) ^ lsw) * 8);
        }

        __builtin_amdgcn_s_setprio(1);
        #pragma unroll
        for (int ks = 0; ks < 2; ks++)
            #pragma unroll
            for (int m = 0; m < 4; m++)
                #pragma unroll
                for (int n = 0; n < 4; n++)
                    acc[m][n] = __builtin_amdgcn_mfma_f32_16x16x32_bf16(
                        af[m][ks], bf[n][ks], acc[m][n], 0, 0, 0);
        __builtin_amdgcn_s_setprio(0);

        asm volatile("s_waitcnt lgkmcnt(0)" ::: "memory");
        __builtin_amdgcn_sched_barrier(0);
        __builtin_amdgcn_s_barrier();          // all waves done reading buf[t%3]
    }
    #undef STAGE

    #pragma unroll
    for (int m = 0; m < 4; m++) {
        const int r0 = wr + m * 16 + lhi * 4;
        #pragma unroll
        for (int n = 0; n < 4; n++) {
            const int c0 = wc + n * 16 + l16;
            #pragma unroll
            for (int j = 0; j < 4; j++)
                Cb[(size_t)(r0 + j) * N2 + c0] = acc[m][n][j];
        }
    }
}

// ---------------------------------------------------------------------------
// row normalize: dinv = rsqrt(rowsum) (0 if rowsum<=0)
// ---------------------------------------------------------------------------
__device__ __forceinline__ float block_sum256(float v) {
    #pragma unroll
    for (int off = 32; off; off >>= 1) v += __shfl_xor(v, off, 64);
    __shared__ float wsum[4];
    if ((threadIdx.x & 63) == 0) wsum[threadIdx.x >> 6] = v;
    __syncthreads();
    return wsum[0] + wsum[1] + wsum[2] + wsum[3];
}

__global__ __launch_bounds__(256) void norm0_kernel(
    const float* __restrict__ H, unsigned short* __restrict__ Hn) {
    const size_t r = blockIdx.x;             // 0..4095 (c*2048 + row)
    const float* hr = H + r * N2;
    const int base = threadIdx.x * 8;
    float v[8];
    #pragma unroll
    for (int i = 0; i < 4; i++) {
        const float2 t = *(const float2*)&hr[base + i * 2];
        v[2 * i] = t.x; v[2 * i + 1] = t.y;
    }
    float s = 0.f;
    #pragma unroll
    for (int i = 0; i < 8; i++) s += v[i];
    const float tot = block_sum256(s);
    const float dinv = tot > 0.f ? rsqrtf(tot) : 0.f;
    ushort4 o0, o1;
    o0.x = f2bf(v[0] * dinv); o0.y = f2bf(v[1] * dinv);
    o0.z = f2bf(v[2] * dinv); o0.w = f2bf(v[3] * dinv);
    o1.x = f2bf(v[4] * dinv); o1.y = f2bf(v[5] * dinv);
    o1.z = f2bf(v[6] * dinv); o1.w = f2bf(v[7] * dinv);
    *(ushort4*)&Hn[r * N2 + base]     = o0;
    *(ushort4*)&Hn[r * N2 + base + 4] = o1;
}

__global__ __launch_bounds__(256) void norm1_kernel(float* __restrict__ H) {
    const size_t r = blockIdx.x;
    float* hr = H + r * N2;
    const int base = threadIdx.x * 8;
    float v[8];
    #pragma unroll
    for (int i = 0; i < 4; i++) {
        const float2 t = *(const float2*)&hr[base + i * 2];
        v[2 * i] = t.x; v[2 * i + 1] = t.y;
    }
    float s = 0.f;
    #pragma unroll
    for (int i = 0; i < 8; i++) s += v[i];
    const float tot = block_sum256(s);
    const float dinv = tot > 0.f ? rsqrtf(tot) : 0.f;
    #pragma unroll
    for (int i = 0; i < 4; i++) {
        float2 t;
        t.x = v[2 * i] * dinv; t.y = v[2 * i + 1] * dinv;
        *(float2*)&hr[base + i * 2] = t;
    }
}

// ---------------------------------------------------------------------------
// head: y[t,o] = lin_b[o] + sum_k relu(X[tx[t]]·gcn_w[k] + gcn_b[k]) *
//                           (lin_w[o,k] + lin_w[o,k+128])
// ---------------------------------------------------------------------------
__global__ __launch_bounds__(128) void head_kernel(
    const float* __restrict__ X, const float* __restrict__ gcn_w,
    const float* __restrict__ gcn_b, const float* __restrict__ lin_w,
    const float* __restrict__ lin_b, const int* __restrict__ tx,
    float* __restrict__ y) {
    __shared__ float xr[512];
    __shared__ float xk[128];
    const int t = blockIdx.x, tid = threadIdx.x;
    const int trg = tx[t];
    const float* Xr = X + (size_t)trg * 512;
    *(float4*)&xr[tid * 4] = *(const float4*)&Xr[tid * 4];
    __syncthreads();
    const float* wr = gcn_w + (size_t)tid * 512;
    float d = 0.f;
    for (int i = 0; i < 512; i += 4) {
        const float4 wv = *(const float4*)&wr[i];
        d += xr[i] * wv.x + xr[i + 1] * wv.y + xr[i + 2] * wv.z + xr[i + 3] * wv.w;
    }
    xk[tid] = fmaxf(d + gcn_b[tid], 0.f);
    __syncthreads();
    if (tid < 8) {
        float a = lin_b[tid];
        for (int k = 0; k < 128; k++)
            a += xk[k] * (lin_w[tid * 256 + k] + lin_w[tid * 256 + 128 + k]);
        y[(size_t)t * 8 + tid] = a;
    }
}

__global__ void wsoft_kernel(const float* __restrict__ w01,
                             const float* __restrict__ w02,
                             const float* __restrict__ w11,
                             float* __restrict__ out) {
    const int tid = threadIdx.x;
    if (tid < 6) {
        const int wi = tid >> 1, c = tid & 1;
        const float* w = (wi == 0 ? w01 : (wi == 1 ? w02 : w11)) + c * 5;
        float mx = w[0];
        for (int e = 1; e < 5; e++) mx = fmaxf(mx, w[e]);
        float ex[5], sum = 0.f;
        for (int e = 0; e < 5; e++) { ex[e] = expf(w[e] - mx); sum += ex[e]; }
        for (int e = 0; e < 5; e++) out[tid * 5 + e] = ex[e] / sum;
    }
}

// ---------------------------------------------------------------------------
extern "C" void kernel_launch(void* const* d_in, const int* in_sizes, int n_in,
                              void* d_out, int out_size, void* d_ws, size_t ws_size,
                              hipStream_t stream) {
    const float* A     = (const float*)d_in[0];
    const float* X     = (const float*)d_in[1];
    const float* w01   = (const float*)d_in[2];
    const float* w02   = (const float*)d_in[3];
    const float* w11   = (const float*)d_in[4];
    const float* gcn_w = (const float*)d_in[5];
    const float* gcn_b = (const float*)d_in[6];
    const float* lin_w = (const float*)d_in[7];
    const float* lin_b = (const float*)d_in[8];
    const int*   tx    = (const int*)d_in[9];

    float* out  = (float*)d_out;
    float* y    = out;           // [512, 8]
    float* allw = out + 4096;    // [3, 2, 5]
    float* H    = out + 4126;    // [2, 2048, 2048] fp32 (GEMM target, normalized in place)

    unsigned short* HA   = (unsigned short*)d_ws;  // [2,N,N] bf16; reused for Hn after layer0
    unsigned short* HBt  = HA + 2 * NN;
    unsigned short* HB2t = HBt + 2 * NN;           // total ws use: 50.3 MB

    combine_kernel<<<dim3(64, 64), 256, 0, stream>>>(A, w01, w02, w11, HA, HBt, HB2t);
    gemm_bt2<<<dim3(16, 8, 2), 512, 0, stream>>>(HA, HBt, H);       // H = HA @ HB
    norm0_kernel<<<4096, 256, 0, stream>>>(H, HA);                   // HA buf := bf16 D^-1/2 H
    gemm_bt2<<<dim3(16, 8, 2), 512, 0, stream>>>(HA, HB2t, H);      // H = Hn @ HB2
    norm1_kernel<<<4096, 256, 0, stream>>>(H);                       // in-place fp32 normalize
    head_kernel<<<512, 128, 0, stream>>>(X, gcn_w, gcn_b, lin_w, lin_b, tx, y);
    wsoft_kernel<<<1, 64, 0, stream>>>(w01, w02, w11, allw);
}

// Round 3
// 147.014 us; speedup vs baseline: 1.2559x; 1.0575x over previous
//
#include <hip/hip_runtime.h>
#include <stdint.h>

#define N2 2048
#define NN (2048UL * 2048UL)

typedef __attribute__((ext_vector_type(8))) short short8;
typedef __attribute__((ext_vector_type(8))) unsigned short u16x8;
typedef __attribute__((ext_vector_type(4))) float f32x4;

__device__ __forceinline__ unsigned short f2bf(float f) {
    unsigned int u = __float_as_uint(f);
    u += 0x7FFFu + ((u >> 16) & 1u);   // round-to-nearest-even
    return (unsigned short)(u >> 16);
}

__device__ __forceinline__ void gload16(const void* g, void* l) {
    __builtin_amdgcn_global_load_lds(
        (const __attribute__((address_space(1))) unsigned int*)g,
        (__attribute__((address_space(3))) unsigned int*)l, 16, 0, 0);
}

// ---------------------------------------------------------------------------
// combine: HA[c][n][m]  = sum_e s1[c][e] A[e][n][m]   (bf16, row-major)
//          HBt[c][m][n] = sum_e s2[c][e] A[e][n][m]   (bf16, transposed)
//          HB2t[c][m][n]= sum_e s3[c][e] A[e][n][m]   (bf16, transposed)
// Block tile: n-extent 64, m-extent 32. One barrier pair; 16B stores.
// ---------------------------------------------------------------------------
__global__ __launch_bounds__(256) void combine_kernel(
    const float* __restrict__ A, const float* __restrict__ w01,
    const float* __restrict__ w02, const float* __restrict__ w11,
    unsigned short* __restrict__ HA, unsigned short* __restrict__ HBt,
    unsigned short* __restrict__ HB2t) {
    __shared__ float s[3][2][5];
    __shared__ float tile[4][64][33];   // 4 transposed outputs, pad 33
    const int tid = threadIdx.x;
    if (tid < 6) {
        const int wi = tid >> 1, c = tid & 1;
        const float* w = (wi == 0 ? w01 : (wi == 1 ? w02 : w11)) + c * 5;
        float mx = w[0];
        for (int e = 1; e < 5; e++) mx = fmaxf(mx, w[e]);
        float ex[5], sum = 0.f;
        for (int e = 0; e < 5; e++) { ex[e] = expf(w[e] - mx); sum += ex[e]; }
        for (int e = 0; e < 5; e++) s[wi][c][e] = ex[e] / sum;
    }
    __syncthreads();

    const int nr = tid >> 2;           // 0..63
    const int mc = (tid & 3) * 8;      // 0,8,16,24
    const size_t gn = (size_t)blockIdx.y * 64 + nr;
    const size_t gm = (size_t)blockIdx.x * 32 + mc;
    const float* ap = A + gn * N2 + gm;

    float acc[6][8] = {};
    #pragma unroll
    for (int e = 0; e < 5; e++) {
        const float4 a0 = *(const float4*)(ap + (size_t)e * NN);
        const float4 a1 = *(const float4*)(ap + (size_t)e * NN + 4);
        const float av[8] = {a0.x, a0.y, a0.z, a0.w, a1.x, a1.y, a1.z, a1.w};
        #pragma unroll
        for (int c = 0; c < 2; c++) {
            const float q0 = s[0][c][e], q1 = s[1][c][e], q2 = s[2][c][e];
            #pragma unroll
            for (int i = 0; i < 8; i++) {
                acc[c][i]     += q0 * av[i];
                acc[2 + c][i] += q1 * av[i];
                acc[4 + c][i] += q2 * av[i];
            }
        }
    }
    // HA row-major, 16B stores
    #pragma unroll
    for (int c = 0; c < 2; c++) {
        u16x8 v;
        #pragma unroll
        for (int i = 0; i < 8; i++) v[i] = f2bf(acc[c][i]);
        *(u16x8*)&HA[(size_t)c * NN + gn * N2 + gm] = v;
    }
    // stage all 4 transposed outputs
    #pragma unroll
    for (int r = 0; r < 4; r++)
        #pragma unroll
        for (int i = 0; i < 8; i++)
            tile[r][nr][mc + i] = acc[2 + r][i];
    __syncthreads();

    const int mrow = tid >> 3;         // 0..31
    const int ns   = (tid & 7) * 8;    // 0..56
    #pragma unroll
    for (int r = 0; r < 4; r++) {
        u16x8 v;
        #pragma unroll
        for (int i = 0; i < 8; i++) v[i] = f2bf(tile[r][ns + i][mrow]);
        unsigned short* dst = (r < 2 ? HBt : HB2t) + (size_t)(r & 1) * NN
            + ((size_t)blockIdx.x * 32 + mrow) * N2
            + (size_t)blockIdx.y * 64 + ns;
        *(u16x8*)dst = v;
    }
}

// ---------------------------------------------------------------------------
// bf16 GEMM, B^T input: C[c] = A[c] @ B[c].
// 256x128 tile, BK=64, 8 waves (4Mx2N), per-wave 64x64 (4x4 frags 16x16x32).
// 3-deep counted-vmcnt pipeline, XOR-swizzled LDS, setprio around MFMA.
// Epilogue: C store (bf16 or fp32) + deterministic per-block partial row sums
// P[bx*2 + colwave][z*2048 + row].
// ---------------------------------------------------------------------------
#define GBM 256
#define GBN 128
#define GBK 64
#define TILE_SHORTS 24576   // 48KB in shorts
#define A_SHORTS    16384   // A region per buffer

template <bool BF16OUT>
__global__ __launch_bounds__(512, 2) void gemm_bt2(
    const unsigned short* __restrict__ A, const unsigned short* __restrict__ Bt,
    void* __restrict__ Cout, float* __restrict__ P) {
    __shared__ unsigned short lds[3 * TILE_SHORTS];   // 144 KB

    const int tid  = threadIdx.x;
    const int wave = tid >> 6, lane = tid & 63;
    const int wr = (wave >> 1) * 64;    // 0,64,128,192
    const int wc = (wave & 1) * 64;     // 0,64
    const int l16 = lane & 15, lhi = lane >> 4;
    const int lsw = l16 & 7;            // row-dependent swizzle bits on read

    const int brow = blockIdx.y * GBM;
    const int bcol = blockIdx.x * GBN;
    const size_t cz = (size_t)blockIdx.z * NN;
    const unsigned short* Ab  = A  + cz + (size_t)brow * N2;
    const unsigned short* Btb = Bt + cz + (size_t)bcol * N2;

    // staging: thread tid handles LDS 16B-slots (i*512+tid); swizzle on source.
    const unsigned short* a_src[4];
    #pragma unroll
    for (int i = 0; i < 4; i++) {
        const int slot = i * 512 + tid;
        const int r = slot >> 3, ssw = (slot & 7) ^ (r & 7);
        a_src[i] = Ab + (size_t)r * N2 + ssw * 8;
    }
    const unsigned short* b_src[2];
    #pragma unroll
    for (int i = 0; i < 2; i++) {
        const int slot = i * 512 + tid;
        const int r = slot >> 3, ssw = (slot & 7) ^ (r & 7);
        b_src[i] = Btb + (size_t)r * N2 + ssw * 8;
    }

    #define STAGE(buf, k0)                                                    \
        do {                                                                  \
            unsigned short* dst = lds + (buf) * TILE_SHORTS + tid * 8;        \
            _Pragma("unroll")                                                 \
            for (int i = 0; i < 4; i++)                                       \
                gload16(a_src[i] + (k0), dst + i * 4096);                     \
            _Pragma("unroll")                                                 \
            for (int i = 0; i < 2; i++)                                       \
                gload16(b_src[i] + (k0), dst + A_SHORTS + i * 4096);          \
        } while (0)

    f32x4 acc[4][4] = {};

    STAGE(0, 0);
    STAGE(1, GBK);

    const int nt = N2 / GBK;   // 32
    for (int t = 0; t < nt; ++t) {
        if (t + 2 < nt) STAGE((t + 2) % 3, (t + 2) * GBK);

        if (t < nt - 2)       asm volatile("s_waitcnt vmcnt(12)" ::: "memory");
        else if (t == nt - 2) asm volatile("s_waitcnt vmcnt(6)"  ::: "memory");
        else                  asm volatile("s_waitcnt vmcnt(0)"  ::: "memory");
        __builtin_amdgcn_s_barrier();          // buf[t%3] ready for all waves

        const unsigned short* base = lds + (t % 3) * TILE_SHORTS;
        short8 af[4][2], bf[4][2];
        #pragma unroll
        for (int m = 0; m < 4; m++) {
            const unsigned short* rowp = base + (wr + m * 16 + l16) * 64;
            #pragma unroll
            for (int ks = 0; ks < 2; ks++)
                af[m][ks] = *(const short8*)(rowp + ((ks * 4 + lhi) ^ lsw) * 8);
        }
        #pragma unroll
        for (int n = 0; n < 4; n++) {
            const unsigned short* rowp = base + A_SHORTS + (wc + n * 16 + l16) * 64;
            #pragma unroll
            for (int ks = 0; ks < 2; ks++)
                bf[n][ks] = *(const short8*)(rowp + ((ks * 4 + lhi) ^ lsw) * 8);
        }

        __builtin_amdgcn_s_setprio(1);
        #pragma unroll
        for (int ks = 0; ks < 2; ks++)
            #pragma unroll
            for (int m = 0; m < 4; m++)
                #pragma unroll
                for (int n = 0; n < 4; n++)
                    acc[m][n] = __builtin_amdgcn_mfma_f32_16x16x32_bf16(
                        af[m][ks], bf[n][ks], acc[m][n], 0, 0, 0);
        __builtin_amdgcn_s_setprio(0);

        asm volatile("s_waitcnt lgkmcnt(0)" ::: "memory");
        __builtin_amdgcn_sched_barrier(0);
        __builtin_amdgcn_s_barrier();          // all waves done reading buf[t%3]
    }
    #undef STAGE

    // ---- C store ----
    if constexpr (BF16OUT) {
        unsigned short* Cb = (unsigned short*)Cout + cz + (size_t)brow * N2 + bcol;
        #pragma unroll
        for (int m = 0; m < 4; m++) {
            const int r0 = wr + m * 16 + lhi * 4;
            #pragma unroll
            for (int n = 0; n < 4; n++) {
                const int c0 = wc + n * 16 + l16;
                #pragma unroll
                for (int j = 0; j < 4; j++)
                    Cb[(size_t)(r0 + j) * N2 + c0] = f2bf(acc[m][n][j]);
            }
        }
    } else {
        float* Cb = (float*)Cout + cz + (size_t)brow * N2 + bcol;
        #pragma unroll
        for (int m = 0; m < 4; m++) {
            const int r0 = wr + m * 16 + lhi * 4;
            #pragma unroll
            for (int n = 0; n < 4; n++) {
                const int c0 = wc + n * 16 + l16;
                #pragma unroll
                for (int j = 0; j < 4; j++)
                    Cb[(size_t)(r0 + j) * N2 + c0] = acc[m][n][j];
            }
        }
    }

    // ---- deterministic partial row sums over this block's 128-col half ----
    const size_t pb = (size_t)(blockIdx.x * 2 + (wave & 1)) * 4096
                    + (size_t)blockIdx.z * 2048 + brow + wr;
    #pragma unroll
    for (int m = 0; m < 4; m++)
        #pragma unroll
        for (int j = 0; j < 4; j++) {
            float ps = acc[m][0][j] + acc[m][1][j] + acc[m][2][j] + acc[m][3][j];
            ps += __shfl_xor(ps, 1);
            ps += __shfl_xor(ps, 2);
            ps += __shfl_xor(ps, 4);
            ps += __shfl_xor(ps, 8);
            if (l16 == 0) P[pb + m * 16 + lhi * 4 + j] = ps;
        }
}

// ---------------------------------------------------------------------------
// dinv0[r] = rsqrt(sum_cb P[cb][r])  (0 if <=0)
// ---------------------------------------------------------------------------
__global__ __launch_bounds__(256) void dinv_kernel(
    const float* __restrict__ P, float* __restrict__ dinv) {
    const int r = blockIdx.x * 256 + threadIdx.x;
    float sum = 0.f;
    #pragma unroll
    for (int cb = 0; cb < 32; cb++) sum += P[cb * 4096 + r];
    dinv[r] = sum > 0.f ? rsqrtf(sum) : 0.f;
}

// sfac[r] = dinv0[r] * rsqrt(dinv0[r] * sum_cb P[cb][r])  (guarded)
__global__ __launch_bounds__(256) void sfac_kernel(
    const float* __restrict__ P, const float* __restrict__ dinv0,
    float* __restrict__ sfac) {
    const int r = blockIdx.x * 256 + threadIdx.x;
    float sum = 0.f;
    #pragma unroll
    for (int cb = 0; cb < 32; cb++) sum += P[cb * 4096 + r];
    const float d0 = dinv0[r];
    const float d1 = d0 * sum;
    sfac[r] = d0 * (d1 > 0.f ? rsqrtf(d1) : 0.f);
}

// final[r][:] = W[r][:] * sfac[r]
__global__ __launch_bounds__(256) void finalize_kernel(
    const float* __restrict__ W, const float* __restrict__ sfac,
    float* __restrict__ H) {
    const size_t r = blockIdx.x;
    const float sc = sfac[r];
    const int base = threadIdx.x * 8;
    const float4 a0 = *(const float4*)&W[r * N2 + base];
    const float4 a1 = *(const float4*)&W[r * N2 + base + 4];
    float4 o0, o1;
    o0.x = a0.x * sc; o0.y = a0.y * sc; o0.z = a0.z * sc; o0.w = a0.w * sc;
    o1.x = a1.x * sc; o1.y = a1.y * sc; o1.z = a1.z * sc; o1.w = a1.w * sc;
    *(float4*)&H[r * N2 + base]     = o0;
    *(float4*)&H[r * N2 + base + 4] = o1;
}

// ---------------------------------------------------------------------------
// head: y[t,o] = lin_b[o] + sum_k relu(X[tx[t]]·gcn_w[k] + gcn_b[k]) *
//                           (lin_w[o,k] + lin_w[o,k+128])
// ---------------------------------------------------------------------------
__global__ __launch_bounds__(128) void head_kernel(
    const float* __restrict__ X, const float* __restrict__ gcn_w,
    const float* __restrict__ gcn_b, const float* __restrict__ lin_w,
    const float* __restrict__ lin_b, const int* __restrict__ tx,
    float* __restrict__ y) {
    __shared__ float xr[512];
    __shared__ float xk[128];
    const int t = blockIdx.x, tid = threadIdx.x;
    const int trg = tx[t];
    const float* Xr = X + (size_t)trg * 512;
    *(float4*)&xr[tid * 4] = *(const float4*)&Xr[tid * 4];
    __syncthreads();
    const float* wr = gcn_w + (size_t)tid * 512;
    float d = 0.f;
    for (int i = 0; i < 512; i += 4) {
        const float4 wv = *(const float4*)&wr[i];
        d += xr[i] * wv.x + xr[i + 1] * wv.y + xr[i + 2] * wv.z + xr[i + 3] * wv.w;
    }
    xk[tid] = fmaxf(d + gcn_b[tid], 0.f);
    __syncthreads();
    if (tid < 8) {
        float a = lin_b[tid];
        for (int k = 0; k < 128; k++)
            a += xk[k] * (lin_w[tid * 256 + k] + lin_w[tid * 256 + 128 + k]);
        y[(size_t)t * 8 + tid] = a;
    }
}

__global__ void wsoft_kernel(const float* __restrict__ w01,
                             const float* __restrict__ w02,
                             const float* __restrict__ w11,
                             float* __restrict__ out) {
    const int tid = threadIdx.x;
    if (tid < 6) {
        const int wi = tid >> 1, c = tid & 1;
        const float* w = (wi == 0 ? w01 : (wi == 1 ? w02 : w11)) + c * 5;
        float mx = w[0];
        for (int e = 1; e < 5; e++) mx = fmaxf(mx, w[e]);
        float ex[5], sum = 0.f;
        for (int e = 0; e < 5; e++) { ex[e] = expf(w[e] - mx); sum += ex[e]; }
        for (int e = 0; e < 5; e++) out[tid * 5 + e] = ex[e] / sum;
    }
}

// ---------------------------------------------------------------------------
extern "C" void kernel_launch(void* const* d_in, const int* in_sizes, int n_in,
                              void* d_out, int out_size, void* d_ws, size_t ws_size,
                              hipStream_t stream) {
    const float* A     = (const float*)d_in[0];
    const float* X     = (const float*)d_in[1];
    const float* w01   = (const float*)d_in[2];
    const float* w02   = (const float*)d_in[3];
    const float* w11   = (const float*)d_in[4];
    const float* gcn_w = (const float*)d_in[5];
    const float* gcn_b = (const float*)d_in[6];
    const float* lin_w = (const float*)d_in[7];
    const float* lin_b = (const float*)d_in[8];
    const int*   tx    = (const int*)d_in[9];

    float* out  = (float*)d_out;
    float* y    = out;                 // [512, 8]
    float* allw = out + 4096;          // [3, 2, 5]
    float* H    = out + 4126;          // [2, 2048, 2048] fp32 final output
    // C0 (bf16, unscaled layer-0 product) lives inside the H region,
    // 16B-aligned (float offset 4128); dead once finalize overwrites H.
    unsigned short* C0 = (unsigned short*)(out + 4128);

    unsigned short* HA   = (unsigned short*)d_ws;       // [2,N,N] bf16
    unsigned short* HBt  = HA + 2 * NN;                 // [2,N,N] bf16 (B^T)
    unsigned short* HB2t = HBt + 2 * NN;                // [2,N,N] bf16 (B^T)
    float* P     = (float*)(HB2t + 2 * NN);             // [32][4096] partials
    float* dinv0 = P + 32 * 4096;                       // [4096]
    float* sfac  = dinv0 + 4096;                        // [4096]
    float* W     = (float*)d_ws;  // fp32 raw layer-1 product; reuses HA+HBt
                                  // (both dead once gemm1 runs: it reads C0+HB2t)

    combine_kernel<<<dim3(64, 32), 256, 0, stream>>>(A, w01, w02, w11, HA, HBt, HB2t);
    gemm_bt2<true><<<dim3(16, 8, 2), 512, 0, stream>>>(HA, HBt, C0, P);    // C0 = HA@HB (bf16) + rowsum partials
    dinv_kernel<<<16, 256, 0, stream>>>(P, dinv0);                         // dinv0 = rsqrt(deg0)
    gemm_bt2<false><<<dim3(16, 8, 2), 512, 0, stream>>>(C0, HB2t, W, P);   // W = C0@HB2 (fp32 raw) + partials
    sfac_kernel<<<16, 256, 0, stream>>>(P, dinv0, sfac);                   // sfac = dinv0*dinv1
    finalize_kernel<<<4096, 256, 0, stream>>>(W, sfac, H);                 // H = sfac ⊙ W
    head_kernel<<<512, 128, 0, stream>>>(X, gcn_w, gcn_b, lin_w, lin_b, tx, y);
    wsoft_kernel<<<1, 64, 0, stream>>>(w01, w02, w11, allw);
}